// Round 1
// baseline (680.879 us; speedup 1.0000x reference)
//
#include <hip/hip_runtime.h>

// SNN LIF, T=1000, B=8192, IN=4, HID=10, OUT=3.
// Strategy: 4 lanes (one quad) per batch element -> 32768 threads = 512 waves.
// Each lane owns 3 (zero-padded to 12) layer-1 neurons; layer-2 current is
// quad-reduced via DPP quad_perm adds (VALU-rate, no LDS). reset_t == spk_{t-1}
// so the reset term is folded into the bias. x prefetched one step ahead.
//
// NOTE (rounds 2-5 of prior session): this kernel's DEVICE CODE is
// byte-identical to the round-1 version, which is the only binary verified to
// match the np reference's spike trajectory exactly (absmax 0.0156, zero spike
// flips). Four attempts to restructure the arithmetic (deeper pipelining,
// explicit fma placement, BLAS-order reconstruction) each produced >=1 spike
// flip vs the reference (errors 0.297 / 1.0 > threshold 0.1775). DO NOT alter
// any expression, loop structure, or launch_bounds in the kernel body.
// Host-side launch geometry changed 128x256 -> 512x64: tid mapping identical
// (blockIdx.x*blockDim.x+threadIdx.x), device codegen untouched; spreads the
// 512 waves over all 256 CUs (2 single-wave blocks/CU) for doubled per-CU
// memory-queue parallelism on this latency-bound binary.
//
// ROUND 0 (this session): previous bench attempt died with "MI355X container
// failed twice" (broker infra) — no timing/counters returned. Source is
// resubmitted UNCHANGED to re-establish the 687.6 µs baseline and capture
// rocprof. Predicted: dur ~688 µs, hbm ~0.47 TB/s (latency-bound, 13x above
// the ~51 µs BW roofline), VALUBusy < 35%, Occupancy ~6%.

#define T_STEPS 1000
#define BATCH   8192
#define IN_DIM  4
#define HID     10
#define OUT_DIM 3
#define BETA    0.95f
#define THR     1.0f

__device__ __forceinline__ float quad_sum(float v) {
    // sum across the 4 lanes of each quad: xor1 then xor2 via DPP quad_perm
    int i = __builtin_bit_cast(int, v);
    int a = __builtin_amdgcn_update_dpp(0, i, 0xB1 /*quad_perm(1,0,3,2)*/, 0xF, 0xF, true);
    v += __builtin_bit_cast(float, a);
    i = __builtin_bit_cast(int, v);
    int b = __builtin_amdgcn_update_dpp(0, i, 0x4E /*quad_perm(2,3,0,1)*/, 0xF, 0xF, true);
    v += __builtin_bit_cast(float, b);
    return v;
}

__global__ __launch_bounds__(256)
void snn_lif_kernel(const float* __restrict__ x,
                    const float* __restrict__ W1,
                    const float* __restrict__ b1,
                    const float* __restrict__ W2,
                    const float* __restrict__ b2,
                    float* __restrict__ out)
{
    const int tid = blockIdx.x * blockDim.x + threadIdx.x;   // 0..32767
    const int bidx = tid >> 2;     // batch element
    const int sub  = tid & 3;      // lane within quad

    // Per-lane weights: neurons h = sub*3 + j (j<3), zero-padded for h >= 10.
    float w1r[3][4], b1r[3], w2r[3][3];
    #pragma unroll
    for (int j = 0; j < 3; ++j) {
        const int h = sub * 3 + j;
        const bool valid = (h < HID);
        #pragma unroll
        for (int i = 0; i < IN_DIM; ++i)
            w1r[j][i] = valid ? W1[h * IN_DIM + i] : 0.0f;
        b1r[j] = valid ? b1[h] : 0.0f;
        #pragma unroll
        for (int o = 0; o < OUT_DIM; ++o)
            w2r[o][j] = valid ? W2[o * HID + h] : 0.0f;
    }
    const float b2r0 = b2[0], b2r1 = b2[1], b2r2 = b2[2];
    float b2r[3] = {b2r0, b2r1, b2r2};

    float mem1[3] = {0.f, 0.f, 0.f};
    float spk1[3] = {0.f, 0.f, 0.f};   // spike == next step's reset
    float mem2[3] = {0.f, 0.f, 0.f};
    float spk2[3] = {0.f, 0.f, 0.f};

    const float4* xp = reinterpret_cast<const float4*>(x) + bidx;
    float* sp = out + (size_t)bidx * OUT_DIM;                       // spk2 rec
    float* mp = sp + (size_t)T_STEPS * BATCH * OUT_DIM;             // mem2 rec

    float4 xv = *xp;
    for (int t = 0; t < T_STEPS; ++t) {
        // prefetch next timestep's x (clamped pointer on last iter)
        const float4* xnp = xp + ((t + 1 < T_STEPS) ? BATCH : 0);
        float4 xn = *xnp;

        // ---- layer 1 (3 neurons per lane) ----
        #pragma unroll
        for (int j = 0; j < 3; ++j) {
            float cur = (b1r[j] - spk1[j])
                      + w1r[j][0] * xv.x + w1r[j][1] * xv.y
                      + w1r[j][2] * xv.z + w1r[j][3] * xv.w;
            mem1[j] = BETA * mem1[j] + cur;
            spk1[j] = (mem1[j] > THR) ? 1.0f : 0.0f;
        }

        // ---- layer 2: partial currents, quad reduce, LIF update ----
        #pragma unroll
        for (int o = 0; o < OUT_DIM; ++o) {
            float p = w2r[o][0] * spk1[0] + w2r[o][1] * spk1[1]
                    + w2r[o][2] * spk1[2];
            float cur2 = quad_sum(p) + (b2r[o] - spk2[o]);
            mem2[o] = BETA * mem2[o] + cur2;
            spk2[o] = (mem2[o] > THR) ? 1.0f : 0.0f;
        }

        if (sub == 0) {
            sp[0] = spk2[0]; sp[1] = spk2[1]; sp[2] = spk2[2];
            mp[0] = mem2[0]; mp[1] = mem2[1]; mp[2] = mem2[2];
        }
        sp += BATCH * OUT_DIM;
        mp += BATCH * OUT_DIM;
        xp = xnp;
        xv = xn;
    }
}

extern "C" void kernel_launch(void* const* d_in, const int* in_sizes, int n_in,
                              void* d_out, int out_size, void* d_ws, size_t ws_size,
                              hipStream_t stream) {
    const float* x  = (const float*)d_in[0];
    const float* W1 = (const float*)d_in[1];
    const float* b1 = (const float*)d_in[2];
    const float* W2 = (const float*)d_in[3];
    const float* b2 = (const float*)d_in[4];
    float* out = (float*)d_out;

    const int threads = BATCH * 4;     // 4 lanes per batch element
    const int block = 64;              // single-wave blocks -> spread over all 256 CUs
    const int grid = threads / block;  // 512 blocks (tid mapping identical to 128x256)
    snn_lif_kernel<<<grid, block, 0, stream>>>(x, W1, b1, W2, b2, out);
}

// Round 3
// 589.862 us; speedup vs baseline: 1.1543x; 1.1543x over previous
//
#include <hip/hip_runtime.h>

// SNN LIF, T=1000, B=8192, IN=4, HID=10, OUT=3.
// Strategy: 4 lanes (one quad) per batch element -> 32768 threads = 512 waves.
// Each lane owns 3 (zero-padded to 12) layer-1 neurons; layer-2 current is
// quad-reduced via DPP quad_perm adds (VALU-rate, no LDS). reset_t == spk_{t-1}
// so the reset term is folded into the bias. x prefetched one step ahead.
//
// FROZEN FUNCTION (confirmed 5-for-5 across sessions): hipcc's fma-contraction
// for this body is context-sensitive. ANY restructuring of the loop — even
// with textually identical FP statements (round-1 PF=8 attempt: one spk1 flip,
// absmax 0.297) — re-rolls a spike-flip lottery vs the np reference. The
// snn_lif_kernel function below is byte-identical to the verified binary
// (absmax 0.015625, zero flips). DO NOT touch it. Optimize only OUTSIDE it.
//
// ROUND 2: counters said latency-bound on the x stream (474 us kernel,
// VALUBusy 10%, 2 waves/CU, FETCH 64 MB vs 128 MB of x -> half the stream
// missed to HBM at ~900 cy). New SEPARATE prewarm kernel streams all of x
// (128 MiB, fits 256 MiB L3) before the main kernel: x loads become L3 hits.
// Main kernel codegen untouched -> numerics provably unchanged.
// Predicted: main dispatch 474 -> 280-360 us, main FETCH <= 30 MB,
// prewarm ~25 us, absmax exactly 0.015625.

#define T_STEPS 1000
#define BATCH   8192
#define IN_DIM  4
#define HID     10
#define OUT_DIM 3
#define BETA    0.95f
#define THR     1.0f

__device__ __forceinline__ float quad_sum(float v) {
    // sum across the 4 lanes of each quad: xor1 then xor2 via DPP quad_perm
    int i = __builtin_bit_cast(int, v);
    int a = __builtin_amdgcn_update_dpp(0, i, 0xB1 /*quad_perm(1,0,3,2)*/, 0xF, 0xF, true);
    v += __builtin_bit_cast(float, a);
    i = __builtin_bit_cast(int, v);
    int b = __builtin_amdgcn_update_dpp(0, i, 0x4E /*quad_perm(2,3,0,1)*/, 0xF, 0xF, true);
    v += __builtin_bit_cast(float, b);
    return v;
}

__global__ __launch_bounds__(256)
void snn_lif_kernel(const float* __restrict__ x,
                    const float* __restrict__ W1,
                    const float* __restrict__ b1,
                    const float* __restrict__ W2,
                    const float* __restrict__ b2,
                    float* __restrict__ out)
{
    const int tid = blockIdx.x * blockDim.x + threadIdx.x;   // 0..32767
    const int bidx = tid >> 2;     // batch element
    const int sub  = tid & 3;      // lane within quad

    // Per-lane weights: neurons h = sub*3 + j (j<3), zero-padded for h >= 10.
    float w1r[3][4], b1r[3], w2r[3][3];
    #pragma unroll
    for (int j = 0; j < 3; ++j) {
        const int h = sub * 3 + j;
        const bool valid = (h < HID);
        #pragma unroll
        for (int i = 0; i < IN_DIM; ++i)
            w1r[j][i] = valid ? W1[h * IN_DIM + i] : 0.0f;
        b1r[j] = valid ? b1[h] : 0.0f;
        #pragma unroll
        for (int o = 0; o < OUT_DIM; ++o)
            w2r[o][j] = valid ? W2[o * HID + h] : 0.0f;
    }
    const float b2r0 = b2[0], b2r1 = b2[1], b2r2 = b2[2];
    float b2r[3] = {b2r0, b2r1, b2r2};

    float mem1[3] = {0.f, 0.f, 0.f};
    float spk1[3] = {0.f, 0.f, 0.f};   // spike == next step's reset
    float mem2[3] = {0.f, 0.f, 0.f};
    float spk2[3] = {0.f, 0.f, 0.f};

    const float4* xp = reinterpret_cast<const float4*>(x) + bidx;
    float* sp = out + (size_t)bidx * OUT_DIM;                       // spk2 rec
    float* mp = sp + (size_t)T_STEPS * BATCH * OUT_DIM;             // mem2 rec

    float4 xv = *xp;
    for (int t = 0; t < T_STEPS; ++t) {
        // prefetch next timestep's x (clamped pointer on last iter)
        const float4* xnp = xp + ((t + 1 < T_STEPS) ? BATCH : 0);
        float4 xn = *xnp;

        // ---- layer 1 (3 neurons per lane) ----
        #pragma unroll
        for (int j = 0; j < 3; ++j) {
            float cur = (b1r[j] - spk1[j])
                      + w1r[j][0] * xv.x + w1r[j][1] * xv.y
                      + w1r[j][2] * xv.z + w1r[j][3] * xv.w;
            mem1[j] = BETA * mem1[j] + cur;
            spk1[j] = (mem1[j] > THR) ? 1.0f : 0.0f;
        }

        // ---- layer 2: partial currents, quad reduce, LIF update ----
        #pragma unroll
        for (int o = 0; o < OUT_DIM; ++o) {
            float p = w2r[o][0] * spk1[0] + w2r[o][1] * spk1[1]
                    + w2r[o][2] * spk1[2];
            float cur2 = quad_sum(p) + (b2r[o] - spk2[o]);
            mem2[o] = BETA * mem2[o] + cur2;
            spk2[o] = (mem2[o] > THR) ? 1.0f : 0.0f;
        }

        if (sub == 0) {
            sp[0] = spk2[0]; sp[1] = spk2[1]; sp[2] = spk2[2];
            mp[0] = mem2[0]; mp[1] = mem2[1]; mp[2] = mem2[2];
        }
        sp += BATCH * OUT_DIM;
        mp += BATCH * OUT_DIM;
        xp = xnp;
        xv = xn;
    }
}

// Separate prewarm kernel: stream all of x through L2/L3 so the main kernel's
// per-step x loads hit Infinity Cache instead of HBM. Compiled independently
// of snn_lif_kernel — main-kernel codegen (and thus numerics) unaffected.
__global__ __launch_bounds__(256)
void prewarm_kernel(const float4* __restrict__ x, int n4)
{
    const int stride = gridDim.x * blockDim.x;
    float acc = 0.0f;
    for (int i = blockIdx.x * blockDim.x + threadIdx.x; i < n4; i += stride) {
        float4 v = x[i];
        acc += v.x + v.y + v.z + v.w;
    }
    // keep the loads live without writing anywhere (rule #17 anti-DCE)
    asm volatile("" :: "v"(acc));
}

extern "C" void kernel_launch(void* const* d_in, const int* in_sizes, int n_in,
                              void* d_out, int out_size, void* d_ws, size_t ws_size,
                              hipStream_t stream) {
    const float* x  = (const float*)d_in[0];
    const float* W1 = (const float*)d_in[1];
    const float* b1 = (const float*)d_in[2];
    const float* W2 = (const float*)d_in[3];
    const float* b2 = (const float*)d_in[4];
    float* out = (float*)d_out;

    // 1) prewarm: pull all of x (128 MiB = 8.39M float4) into L3
    const int n4 = T_STEPS * BATCH;            // number of float4 in x
    prewarm_kernel<<<2048, 256, 0, stream>>>((const float4*)x, n4);

    // 2) main kernel — device code byte-identical to the verified binary
    const int threads = BATCH * 4;     // 4 lanes per batch element
    const int block = 64;              // single-wave blocks -> spread over all 256 CUs
    const int grid = threads / block;  // 512 blocks
    snn_lif_kernel<<<grid, block, 0, stream>>>(x, W1, b1, W2, b2, out);
}

// Round 6
// 547.289 us; speedup vs baseline: 1.2441x; 1.0778x over previous
//
#include <hip/hip_runtime.h>

// SNN LIF, T=1000, B=8192, IN=4, HID=10, OUT=3.
// Strategy: 4 lanes (one quad) per batch element -> 32768 threads = 512 waves.
// Each lane owns 3 (zero-padded to 12) layer-1 neurons; layer-2 current is
// quad-reduced via DPP quad_perm adds. reset_t == spk_{t-1} folded into bias.
// x prefetched one step ahead (depth-1).
//
// NUMERICS LEDGER (do not re-litigate):
//  - Verified depth-1 FP body: absmax 0.015625, zero spike flips. FROZEN.
//  - The np reference has ONE hyper-marginal threshold site; ANY rounding
//    trajectory other than the verified binary's flips it -> absmax 0.296875.
//    Proven by R2 (PF=8 natural), R4 (PF=8 all-fmaf), R5 (PF=8 contract-off,
//    fmaf chain + separate mem) ALL failing with IDENTICAL 0.296875 despite
//    provably different rounding patterns. The verified binary's exact
//    instruction mix is not reproducible by source-level reasoning (R4 wrote
//    the canonical all-fma chain and still missed). 0/5 restructure attempts
//    across two sessions. DO NOT restructure the time loop or alter any FP
//    expression. Loop-structure changes are a ~80%-fail lottery.
//
// PERF LEDGER:
//  - R1 baseline: 474 us kernel. Latency-bound (VALUBusy 10%, HBM 7%,
//    2 waves/CU; 1138 cyc/step vs ~100 cyc compute; depth-1 prefetch).
//  - R3 (+L3 prewarm of x): 347 us. FETCH_SIZE stayed 64 MB: the 187.5 MB
//    output stream write-allocates through L3 and evicts late-t x slabs
//    before use -> half the x loads still miss to HBM (~900 cyc).
//  - R6 (this round): output stores -> __builtin_nontemporal_store. Stores
//    bypass L3 allocation; x stays fully L3-resident post-prewarm; every
//    per-step load becomes an L3 hit. NT is store-node metadata only: FP
//    instruction selection (fma contraction) is untouched -> numerics should
//    be bit-identical to the verified binary.
//    Predicted: pass @ absmax 0.015625 exactly; main 347 -> 210-270 us;
//    FETCH 64 MB -> <16 MB; WRITE ~192 MB unchanged.
//    If it fails at 0.296875: nt metadata perturbed codegen -> revert to R3
//    source and accept ~347 us as the floor.

#define T_STEPS 1000
#define BATCH   8192
#define IN_DIM  4
#define HID     10
#define OUT_DIM 3
#define BETA    0.95f
#define THR     1.0f

__device__ __forceinline__ float quad_sum(float v) {
    // sum across the 4 lanes of each quad: xor1 then xor2 via DPP quad_perm
    int i = __builtin_bit_cast(int, v);
    int a = __builtin_amdgcn_update_dpp(0, i, 0xB1 /*quad_perm(1,0,3,2)*/, 0xF, 0xF, true);
    v += __builtin_bit_cast(float, a);
    i = __builtin_bit_cast(int, v);
    int b = __builtin_amdgcn_update_dpp(0, i, 0x4E /*quad_perm(2,3,0,1)*/, 0xF, 0xF, true);
    v += __builtin_bit_cast(float, b);
    return v;
}

__global__ __launch_bounds__(256)
void snn_lif_kernel(const float* __restrict__ x,
                    const float* __restrict__ W1,
                    const float* __restrict__ b1,
                    const float* __restrict__ W2,
                    const float* __restrict__ b2,
                    float* __restrict__ out)
{
    const int tid = blockIdx.x * blockDim.x + threadIdx.x;   // 0..32767
    const int bidx = tid >> 2;     // batch element
    const int sub  = tid & 3;      // lane within quad

    // Per-lane weights: neurons h = sub*3 + j (j<3), zero-padded for h >= 10.
    float w1r[3][4], b1r[3], w2r[3][3];
    #pragma unroll
    for (int j = 0; j < 3; ++j) {
        const int h = sub * 3 + j;
        const bool valid = (h < HID);
        #pragma unroll
        for (int i = 0; i < IN_DIM; ++i)
            w1r[j][i] = valid ? W1[h * IN_DIM + i] : 0.0f;
        b1r[j] = valid ? b1[h] : 0.0f;
        #pragma unroll
        for (int o = 0; o < OUT_DIM; ++o)
            w2r[o][j] = valid ? W2[o * HID + h] : 0.0f;
    }
    const float b2r0 = b2[0], b2r1 = b2[1], b2r2 = b2[2];
    float b2r[3] = {b2r0, b2r1, b2r2};

    float mem1[3] = {0.f, 0.f, 0.f};
    float spk1[3] = {0.f, 0.f, 0.f};   // spike == next step's reset
    float mem2[3] = {0.f, 0.f, 0.f};
    float spk2[3] = {0.f, 0.f, 0.f};

    const float4* xp = reinterpret_cast<const float4*>(x) + bidx;
    float* sp = out + (size_t)bidx * OUT_DIM;                       // spk2 rec
    float* mp = sp + (size_t)T_STEPS * BATCH * OUT_DIM;             // mem2 rec

    float4 xv = *xp;
    for (int t = 0; t < T_STEPS; ++t) {
        // prefetch next timestep's x (clamped pointer on last iter)
        const float4* xnp = xp + ((t + 1 < T_STEPS) ? BATCH : 0);
        float4 xn = *xnp;

        // ---- layer 1 (3 neurons per lane) ----  [FROZEN FP TEXT]
        #pragma unroll
        for (int j = 0; j < 3; ++j) {
            float cur = (b1r[j] - spk1[j])
                      + w1r[j][0] * xv.x + w1r[j][1] * xv.y
                      + w1r[j][2] * xv.z + w1r[j][3] * xv.w;
            mem1[j] = BETA * mem1[j] + cur;
            spk1[j] = (mem1[j] > THR) ? 1.0f : 0.0f;
        }

        // ---- layer 2: partial currents, quad reduce, LIF update ----
        #pragma unroll
        for (int o = 0; o < OUT_DIM; ++o) {
            float p = w2r[o][0] * spk1[0] + w2r[o][1] * spk1[1]
                    + w2r[o][2] * spk1[2];
            float cur2 = quad_sum(p) + (b2r[o] - spk2[o]);
            mem2[o] = BETA * mem2[o] + cur2;
            spk2[o] = (mem2[o] > THR) ? 1.0f : 0.0f;
        }

        if (sub == 0) {
            // Nontemporal: bypass L3 allocation so the output stream does not
            // evict the prewarmed x. Store-node metadata only; FP codegen
            // untouched.
            __builtin_nontemporal_store(spk2[0], &sp[0]);
            __builtin_nontemporal_store(spk2[1], &sp[1]);
            __builtin_nontemporal_store(spk2[2], &sp[2]);
            __builtin_nontemporal_store(mem2[0], &mp[0]);
            __builtin_nontemporal_store(mem2[1], &mp[1]);
            __builtin_nontemporal_store(mem2[2], &mp[2]);
        }
        sp += BATCH * OUT_DIM;
        mp += BATCH * OUT_DIM;
        xp = xnp;
        xv = xn;
    }
}

// Separate prewarm kernel: stream all of x through L2/L3 so the main kernel's
// x loads hit Infinity Cache instead of HBM (round 3: -127 us).
__global__ __launch_bounds__(256)
void prewarm_kernel(const float4* __restrict__ x, int n4)
{
    const int stride = gridDim.x * blockDim.x;
    float acc = 0.0f;
    for (int i = blockIdx.x * blockDim.x + threadIdx.x; i < n4; i += stride) {
        float4 v = x[i];
        acc += v.x + v.y + v.z + v.w;
    }
    // keep the loads live without writing anywhere (rule #17 anti-DCE)
    asm volatile("" :: "v"(acc));
}

extern "C" void kernel_launch(void* const* d_in, const int* in_sizes, int n_in,
                              void* d_out, int out_size, void* d_ws, size_t ws_size,
                              hipStream_t stream) {
    const float* x  = (const float*)d_in[0];
    const float* W1 = (const float*)d_in[1];
    const float* b1 = (const float*)d_in[2];
    const float* W2 = (const float*)d_in[3];
    const float* b2 = (const float*)d_in[4];
    float* out = (float*)d_out;

    // 1) prewarm: pull all of x (128 MiB = 8.19M float4) into L3
    const int n4 = T_STEPS * BATCH;            // number of float4 in x
    prewarm_kernel<<<2048, 256, 0, stream>>>((const float4*)x, n4);

    // 2) main kernel — FP body frozen; stores nontemporal
    const int threads = BATCH * 4;     // 4 lanes per batch element
    const int block = 64;              // single-wave blocks -> spread over all 256 CUs
    const int grid = threads / block;  // 512 blocks
    snn_lif_kernel<<<grid, block, 0, stream>>>(x, W1, b1, W2, b2, out);
}